// Round 14
// baseline (403.290 us; speedup 1.0000x reference)
//
#include <hip/hip_runtime.h>

#define D_ 1536
#define H_ 8

typedef __attribute__((ext_vector_type(8))) short bf16x8;
typedef __attribute__((ext_vector_type(4))) float f32x4;

__device__ __forceinline__ unsigned short f2bf(float f) {
    unsigned u = __builtin_bit_cast(unsigned, f);
    unsigned r = (u + 0x7fffu + ((u >> 16) & 1u)) >> 16;
    return (unsigned short)r;
}

__device__ __forceinline__ unsigned pack2bf(float a, float b) {
    return (unsigned)f2bf(a) | ((unsigned)f2bf(b) << 16);
}

__device__ __forceinline__ float bflo(unsigned u) { return __builtin_bit_cast(float, u << 16); }
__device__ __forceinline__ float bfhi(unsigned u) { return __builtin_bit_cast(float, u & 0xffff0000u); }

__device__ __forceinline__ void gload16(const void* g, void* l) {
    __builtin_amdgcn_global_load_lds((const __attribute__((address_space(1))) void*)g,
                                     (__attribute__((address_space(3))) void*)l, 16, 0, 0);
}

// =================== merged preprocessing: Vdst + transposes + Vsrc + edge COUNT ============
// block ranges (flattened blockIdx.x):
//   [0, 1536)   : Vdst rows (reads W_gd)
//   [0, 4608)   : (after -=) W_gs transpose -> BTg + Vsrc atomics
//   [+576)      : W_rel -> BT1            [+576) : W_root -> BT1+D_      [+384) : W1 -> BTw1
//   [>=6144)    : edge counting (atomics)
__global__ __launch_bounds__(256) void k_prep(const float* __restrict__ W_gd,
                                              const float* __restrict__ att_d,
                                              float* __restrict__ Vdst,
                                              const float* __restrict__ W_gs,
                                              const float* __restrict__ att_s,
                                              float* __restrict__ Vsrc,
                                              unsigned short* __restrict__ BTg,
                                              const float* __restrict__ W_rel,
                                              const float* __restrict__ W_root,
                                              unsigned short* __restrict__ BT1,
                                              const float* __restrict__ W1,
                                              unsigned short* __restrict__ BTw1,
                                              const int* __restrict__ edj, int EJ,
                                              const int* __restrict__ edr, int ER,
                                              int* cnt_j, int* cnt_r) {
    __shared__ float t[64][65];
    __shared__ float red[4][H_];
    int r = blockIdx.x;

    if (r < D_) {
        int d = r;
        const float4* wr = (const float4*)(W_gd + (size_t)d * (H_ * D_));
        int tid = threadIdx.x;
        float part[H_];
        #pragma unroll
        for (int h = 0; h < H_; h++) {
            const float4* ar = (const float4*)(att_d + h * D_);
            float4 w0 = wr[h * 384 + tid];
            float4 a0 = ar[tid];
            float s = w0.x * a0.x + w0.y * a0.y + w0.z * a0.z + w0.w * a0.w;
            if (tid < 128) {
                float4 w1 = wr[h * 384 + 256 + tid];
                float4 a1 = ar[256 + tid];
                s += w1.x * a1.x + w1.y * a1.y + w1.z * a1.z + w1.w * a1.w;
            }
            part[h] = s;
        }
        int lane = tid & 63, w = tid >> 6;
        #pragma unroll
        for (int h = 0; h < H_; h++) {
            float v = part[h];
            for (int o = 32; o; o >>= 1) v += __shfl_down(v, o);
            if (lane == 0) red[w][h] = v;
        }
        __syncthreads();
        if (tid < H_) Vdst[d * H_ + tid] = red[0][tid] + red[1][tid] + red[2][tid] + red[3][tid];
        return;
    }
    r -= D_;

    if (r >= 6144) {
        // edge counting
        int i = (r - 6144) * 256 + threadIdx.x;
        if (i < EJ) atomicAdd(&cnt_j[edj[i]], 1);
        else if (i < EJ + ER) atomicAdd(&cnt_r[edr[i - EJ]], 1);
        return;
    }

    const float* in; int ldin; unsigned short* out; int ldout; int nx; int gatb;
    if (r < 4608)               { in = W_gs;  ldin = 0;   out = BTg;      ldout = H_ * D_; nx = 24; gatb = 1; }
    else if ((r -= 4608) < 576) { in = W_rel; ldin = D_;  out = BT1;      ldout = 2 * D_;  nx = 24; gatb = 0; }
    else if ((r -= 576) < 576)  { in = W_root;ldin = D_;  out = BT1 + D_; ldout = 2 * D_;  nx = 24; gatb = 0; }
    else { r -= 576;              in = W1;    ldin = 512; out = BTw1;     ldout = 2 * D_;  nx = 8;  gatb = 0; }

    int n0 = (r % nx) * 64, k0 = (r / nx) * 64;
    int tx = threadIdx.x & 63, ty = threadIdx.x >> 6;
    #pragma unroll
    for (int i = 0; i < 16; i++) {
        int k = k0 + ty + i * 4;
        const float* rp;
        if (gatb) {
            int d2 = k % D_, h = k / D_;
            rp = in + (size_t)d2 * (H_ * D_) + (size_t)h * D_;
        } else {
            rp = in + (size_t)k * ldin;
        }
        t[ty + i * 4][tx] = rp[n0 + tx];
    }
    __syncthreads();
    int tx2 = threadIdx.x & 31, ty2 = threadIdx.x >> 5;
    #pragma unroll
    for (int i = 0; i < 8; i++) {
        int nl = ty2 + i * 8;
        unsigned v = pack2bf(t[tx2 * 2][nl], t[tx2 * 2 + 1][nl]);
        *(unsigned*)(out + (size_t)(n0 + nl) * ldout + k0 + tx2 * 2) = v;
    }
    if (gatb) {
        int h = k0 / D_, d2b = k0 - h * D_;
        int kl = threadIdx.x >> 2, q = threadIdx.x & 3;
        const float* ar = att_s + (size_t)h * D_ + n0 + q * 16;
        float s = 0.f;
        #pragma unroll
        for (int i = 0; i < 16; i++) s += t[kl][q * 16 + i] * ar[i];
        s += __shfl_xor(s, 1);
        s += __shfl_xor(s, 2);
        if (q == 0) atomicAdd(&Vsrc[(size_t)(d2b + kl) * H_ + h], s);
    }
}

// ---- merged: a_src/a_dst projections (+ xsb) AND the two prefix-sum scan blocks ----
__global__ __launch_bounds__(256) void k_a2(const float* __restrict__ xs,
                                            const float* __restrict__ xr,
                                            const float* __restrict__ Vs,
                                            const float* __restrict__ Vd,
                                            float* __restrict__ a_s,
                                            float* __restrict__ a_d,
                                            unsigned* __restrict__ xb, int NS, int NPn,
                                            const int* __restrict__ cnt_j, int* off_j,
                                            const int* __restrict__ cnt_r, int* off_r) {
    int n = blockIdx.x;
    if (n >= NS + NPn) {
        // scan job (2 blocks, wave 0 only)
        if (threadIdx.x >= 64) return;
        int which = n - NS - NPn;
        const int* cnt = which ? cnt_r : cnt_j;
        int* off = which ? off_r : off_j;
        int lane = threadIdx.x;
        int chunk = (NPn + 63) / 64;
        int base = lane * chunk;
        int sum = 0;
        for (int i = 0; i < chunk; i++) { int idx = base + i; if (idx < NPn) sum += cnt[idx]; }
        int incl = sum;
        for (int o = 1; o < 64; o <<= 1) { int t = __shfl_up(incl, o); if (lane >= o) incl += t; }
        int run = incl - sum;
        for (int i = 0; i < chunk; i++) { int idx = base + i; if (idx < NPn) { off[idx] = run; run += cnt[idx]; } }
        if (lane == 63) off[NPn] = run;
        return;
    }
    int skill = n < NS;
    int row = skill ? n : n - NS;
    const float2* xrow = (const float2*)(skill ? xs : xr) + (size_t)row * 768;
    const float* V = skill ? Vs : Vd;
    float* out = (skill ? a_s : a_d) + (size_t)row * H_;
    unsigned* ob = xb + (size_t)row * 768;
    float part[H_] = {};
    #pragma unroll
    for (int j = 0; j < 3; j++) {
        int e = threadIdx.x + j * 256;
        float2 v = xrow[e];
        if (skill) ob[e] = pack2bf(v.x, v.y);
        const float* vp = V + (size_t)(2 * e) * H_;
        #pragma unroll
        for (int h = 0; h < H_; h++) part[h] += v.x * vp[h] + v.y * vp[h + H_];
    }
    __shared__ float red[4][H_];
    int lane = threadIdx.x & 63, w = threadIdx.x >> 6;
    #pragma unroll
    for (int h = 0; h < H_; h++) {
        float v = part[h];
        for (int o = 32; o; o >>= 1) v += __shfl_down(v, o);
        if (lane == 0) red[w][h] = v;
    }
    __syncthreads();
    if (threadIdx.x < H_) out[threadIdx.x] =
        red[0][threadIdx.x] + red[1][threadIdx.x] + red[2][threadIdx.x] + red[3][threadIdx.x];
}

// scatter: sorted-order edge ids (resume) + sorted-order SOURCE ids (both)
__global__ void k_scatter(const int* __restrict__ dj, const int* __restrict__ sj, int ej,
                          const int* __restrict__ dr, const int* __restrict__ sr, int er,
                          const int* __restrict__ off_j, int* fill_j, int* srcv_j,
                          const int* __restrict__ off_r, int* fill_r, int* sid_r, int* srcv_r) {
    int i = blockIdx.x * blockDim.x + threadIdx.x;
    if (i < ej) {
        int p = dj[i];
        int slot = atomicAdd(&fill_j[p], 1);
        srcv_j[off_j[p] + slot] = sj[i];
    } else if (i < ej + er) {
        int e = i - ej;
        int p = dr[e];
        int slot = atomicAdd(&fill_r[p], 1);
        int idx = off_r[p] + slot;
        sid_r[idx] = e;
        srcv_r[idx] = sr[e];
    }
}

// ---- merged aggregates + inlined segment softmax. grid (NP, 6). y<3: GraphConv; y>=3: attn --
__global__ __launch_bounds__(256) void k_aggs(const unsigned* __restrict__ xb,
                                              const int* __restrict__ srcv_j,
                                              const int* __restrict__ cnt_j, const int* __restrict__ off_j,
                                              const int* __restrict__ srcv_r,
                                              const int* __restrict__ sid_r,
                                              const int* __restrict__ cnt_r, const int* __restrict__ off_r,
                                              const float* __restrict__ a_src,
                                              const float* __restrict__ a_dst,
                                              const float* __restrict__ x_job,
                                              unsigned* __restrict__ cat_u,
                                              unsigned* __restrict__ aggatt_u,
                                              float* __restrict__ alpha_out) {
    int p = blockIdx.x;
    if (blockIdx.y < 3) {
        int col = blockIdx.y * 256 + threadIdx.x;
        int n = cnt_j[p], o = off_j[p];
        float2 acc = {0.f, 0.f};
        int i = 0;
        for (; i + 2 <= n; i += 2) {
            unsigned v0 = xb[(size_t)srcv_j[o + i] * 768 + col];
            unsigned v1 = xb[(size_t)srcv_j[o + i + 1] * 768 + col];
            acc.x += bflo(v0) + bflo(v1);
            acc.y += bfhi(v0) + bfhi(v1);
        }
        if (i < n) {
            unsigned v = xb[(size_t)srcv_j[o + i] * 768 + col];
            acc.x += bflo(v); acc.y += bfhi(v);
        }
        unsigned* orow = cat_u + (size_t)p * 1536;
        orow[col] = pack2bf(acc.x, acc.y);
        float2 vj = ((const float2*)x_job)[(size_t)p * 768 + col];
        orow[768 + col] = pack2bf(vj.x, vj.y);
        return;
    }

    // ---------------- attention branch ----------------
    __shared__ float al[1024][H_];        // per-segment alpha scratch (n <= 1024; data has n ~ 16)
    int n = cnt_r[p], o = off_r[p];
    int tid = threadIdx.x;

    if (tid < 64 && n > 0) {
        int lane = tid;
        float4 ad0 = *(const float4*)(a_dst + (size_t)p * H_);
        float4 ad1 = *(const float4*)(a_dst + (size_t)p * H_ + 4);
        float adv[8] = {ad0.x, ad0.y, ad0.z, ad0.w, ad1.x, ad1.y, ad1.z, ad1.w};
        float mx[8];
        #pragma unroll
        for (int h = 0; h < H_; h++) mx[h] = -3.4e38f;
        for (int base = 0; base < n; base += 64) {
            int i = base + lane;
            if (i < n) {
                int s = srcv_r[o + i];
                float4 s0 = *(const float4*)(a_src + (size_t)s * H_);
                float4 s1 = *(const float4*)(a_src + (size_t)s * H_ + 4);
                float sv[8] = {s0.x, s0.y, s0.z, s0.w, s1.x, s1.y, s1.z, s1.w};
                #pragma unroll
                for (int h = 0; h < H_; h++) {
                    float t = sv[h] + adv[h];
                    t = t >= 0.f ? t : 0.2f * t;
                    al[i][h] = t;
                    mx[h] = fmaxf(mx[h], t);
                }
            }
        }
        #pragma unroll
        for (int h = 0; h < H_; h++)
            for (int o2 = 32; o2; o2 >>= 1) mx[h] = fmaxf(mx[h], __shfl_xor(mx[h], o2));
        float sm[8] = {};
        for (int base = 0; base < n; base += 64) {
            int i = base + lane;
            if (i < n) {
                #pragma unroll
                for (int h = 0; h < H_; h++) {
                    float e = expf(al[i][h] - mx[h]);
                    al[i][h] = e;
                    sm[h] += e;
                }
            }
        }
        float inv[8];
        #pragma unroll
        for (int h = 0; h < H_; h++) {
            for (int o2 = 32; o2; o2 >>= 1) sm[h] += __shfl_xor(sm[h], o2);
            inv[h] = 1.f / (sm[h] + 1e-16f);
        }
        for (int base = 0; base < n; base += 64) {
            int i = base + lane;
            if (i < n) {
                float a[8];
                #pragma unroll
                for (int h = 0; h < H_; h++) { a[h] = al[i][h] * inv[h]; al[i][h] = a[h]; }
                if (blockIdx.y == 3) {
                    int e = sid_r[o + i];
                    *(float4*)(alpha_out + (size_t)e * H_) = make_float4(a[0], a[1], a[2], a[3]);
                    *(float4*)(alpha_out + (size_t)e * H_ + 4) = make_float4(a[4], a[5], a[6], a[7]);
                }
            }
        }
    }
    __syncthreads();

    int col = (blockIdx.y - 3) * 256 + tid;
    float2 acc[H_] = {};
    int i = 0;
    for (; i + 2 <= n; i += 2) {
        unsigned v0 = xb[(size_t)srcv_r[o + i] * 768 + col];
        unsigned v1 = xb[(size_t)srcv_r[o + i + 1] * 768 + col];
        float l0 = bflo(v0), h0 = bfhi(v0), l1 = bflo(v1), h1 = bfhi(v1);
        #pragma unroll
        for (int h = 0; h < H_; h++) {
            float w0 = al[i][h], w1 = al[i + 1][h];
            acc[h].x += w0 * l0 + w1 * l1;
            acc[h].y += w0 * h0 + w1 * h1;
        }
    }
    if (i < n) {
        unsigned v0 = xb[(size_t)srcv_r[o + i] * 768 + col];
        float l0 = bflo(v0), h0 = bfhi(v0);
        #pragma unroll
        for (int h = 0; h < H_; h++) { acc[h].x += al[i][h] * l0; acc[h].y += al[i][h] * h0; }
    }
    unsigned* orow = aggatt_u + (size_t)p * (H_ * 768);
    #pragma unroll
    for (int h = 0; h < H_; h++)
        orow[h * 768 + col] = pack2bf(acc[h].x, acc[h].y);
}

// ---------------- bf16 MFMA GEMM (R11-exact): BM=256 BN=128, 8 waves, split-K, 3-buf 2-deep --
__global__ __launch_bounds__(512, 4) void gemm_sk(const unsigned short* __restrict__ A, int lda,
                                                  const unsigned short* __restrict__ BT, int ldb,
                                                  float* __restrict__ P, int N, int bs, int extra) {
    __shared__ unsigned short As[3][256 * 32];
    __shared__ unsigned short Bs[3][128 * 32];
    int tid = threadIdx.x;
    int lane = tid & 63, wid = tid >> 6;

    int nwg = gridDim.x * gridDim.y;
    int bidh = blockIdx.y * gridDim.x + blockIdx.x;
    int swz = (bidh & 7) * (nwg >> 3) + (bidh >> 3);
    int bn = (swz % gridDim.x) * 128;
    int bm = (swz / gridDim.x) * 256;

    int z = blockIdx.z;
    int nt = bs + (z < extra);
    int kb = z * bs + min(z, extra);
    int kbase = kb * 32;

    int wr = wid >> 1, wc = wid & 1;            // 4 x 2 wave grid, wave tile 64x64
    int fr = lane & 15, g = lane >> 4;

    int ra0 = tid >> 2, sa0 = tid & 3;
    int ra1 = (tid + 512) >> 2;
    int sg_a0 = sa0 ^ ((ra0 >> 1) & 3);
    int sg_a1 = sa0 ^ ((ra1 >> 1) & 3);
    int sg_b = sg_a0;

    f32x4 acc[4][4] = {};

    auto stage = [&](int buf, int k0) {
        gload16(A + (size_t)(bm + ra0) * lda + k0 + sg_a0 * 8, &As[buf][tid * 8]);
        gload16(A + (size_t)(bm + ra1) * lda + k0 + sg_a1 * 8, &As[buf][(tid + 512) * 8]);
        gload16(BT + (size_t)(bn + ra0) * ldb + k0 + sg_b * 8, &Bs[buf][tid * 8]);
    };

    stage(0, kbase);
    if (nt > 1) stage(1, kbase + 32);
    for (int t = 0; t < nt; t++) {
        if (t + 2 < nt) {
            stage((t + 2) % 3, kbase + (t + 2) * 32);
            asm volatile("s_waitcnt vmcnt(6)" ::: "memory");   // oldest stage (t) landed
        } else if (t + 1 < nt) {
            asm volatile("s_waitcnt vmcnt(3)" ::: "memory");
        } else {
            asm volatile("s_waitcnt vmcnt(0)" ::: "memory");
        }
        __builtin_amdgcn_s_barrier();
        __builtin_amdgcn_sched_barrier(0);
        int cur = t % 3;
        bf16x8 a[4], b[4];
        #pragma unroll
        for (int mi = 0; mi < 4; mi++) {
            int row = wr * 64 + mi * 16 + fr;
            a[mi] = *(const bf16x8*)(&As[cur][row * 32 + ((g ^ ((row >> 1) & 3)) * 8)]);
        }
        #pragma unroll
        for (int ni = 0; ni < 4; ni++) {
            int row = wc * 64 + ni * 16 + fr;
            b[ni] = *(const bf16x8*)(&Bs[cur][row * 32 + ((g ^ ((row >> 1) & 3)) * 8)]);
        }
        __builtin_amdgcn_s_setprio(1);
        #pragma unroll
        for (int mi = 0; mi < 4; mi++)
            #pragma unroll
            for (int ni = 0; ni < 4; ni++)
                acc[mi][ni] = __builtin_amdgcn_mfma_f32_16x16x32_bf16(a[mi], b[ni], acc[mi][ni], 0, 0, 0);
        __builtin_amdgcn_s_setprio(0);
        __builtin_amdgcn_s_barrier();
        __builtin_amdgcn_sched_barrier(0);
    }

    size_t MN = (size_t)N * (size_t)(gridDim.y * 256);
    float* Pz = P + (size_t)z * MN;
    #pragma unroll
    for (int mi = 0; mi < 4; mi++) {
        int r0 = bm + wr * 64 + mi * 16 + (lane >> 4) * 4;
        #pragma unroll
        for (int ni = 0; ni < 4; ni++) {
            int c = bn + wc * 64 + ni * 16 + (lane & 15);
            #pragma unroll
            for (int j = 0; j < 4; j++)
                Pz[(size_t)(r0 + j) * N + c] = acc[mi][ni][j];
        }
    }
}

// ---------------- split-K reduce + epilogue (big GEMMs) ----------------
template <int OUT_BF16>
__global__ __launch_bounds__(256) void k_reduce(const float* __restrict__ P, int S, int MN, int N,
                                                void* __restrict__ Cout, int ldc,
                                                const float* __restrict__ bias, float scale,
                                                int useLeaky) {
    int idx = (blockIdx.x * 256 + threadIdx.x) * 4;
    if (idx >= MN) return;
    float4 v = *(const float4*)(P + idx);
    for (int s = 1; s < S; s++) {
        float4 t = *(const float4*)(P + (size_t)s * MN + idx);
        v.x += t.x; v.y += t.y; v.z += t.z; v.w += t.w;
    }
    int m = idx / N, n = idx - m * N;
    float vv[4] = {v.x, v.y, v.z, v.w};
    #pragma unroll
    for (int j = 0; j < 4; j++) {
        float x = vv[j] * scale + bias[n + j];
        if (useLeaky) x = x >= 0.f ? x : 0.01f * x;
        if (OUT_BF16) ((unsigned short*)Cout)[(size_t)m * ldc + n + j] = f2bf(x);
        else ((float*)Cout)[(size_t)m * ldc + n + j] = x;
    }
}

// ---- fused: h1 split-K reduce (8 slabs) + b1 + leaky + MLP2 + score ----
__global__ __launch_bounds__(256) void k_mlp2(const float* __restrict__ P, int MN1,
                                              const float* __restrict__ b1,
                                              const float* __restrict__ W2,
                                              const float* __restrict__ b2,
                                              const float* __restrict__ W3,
                                              const float* __restrict__ b3,
                                              float* __restrict__ score) {
    __shared__ unsigned h1s[8][256];
    __shared__ float red[4][4];
    int p0 = blockIdx.x * 8;
    int tid = threadIdx.x;
    #pragma unroll
    for (int i = 0; i < 8; i++) {
        int idx = tid + i * 256;
        int row = idx >> 8, c2 = idx & 255;
        size_t base = (size_t)(p0 + row) * 512 + 2 * c2;
        float2 v = {0.f, 0.f};
        #pragma unroll
        for (int s = 0; s < 8; s++) {
            float2 t = *(const float2*)(P + (size_t)s * MN1 + base);
            v.x += t.x; v.y += t.y;
        }
        float2 bb = *(const float2*)(b1 + 2 * c2);
        v.x += bb.x; v.y += bb.y;
        v.x = v.x >= 0.f ? v.x : 0.01f * v.x;
        v.y = v.y >= 0.f ? v.y : 0.01f * v.y;
        h1s[row][c2] = pack2bf(v.x, v.y);
    }
    __syncthreads();
    int c = tid & 127, rg = tid >> 7;
    float acc[4] = {};
    for (int k = 0; k < 512; k += 2) {
        float w0 = W2[(size_t)k * 128 + c];
        float w1 = W2[(size_t)(k + 1) * 128 + c];
        #pragma unroll
        for (int r = 0; r < 4; r++) {
            unsigned hv = h1s[rg * 4 + r][k >> 1];
            acc[r] += bflo(hv) * w0 + bfhi(hv) * w1;
        }
    }
    float w3 = W3[c];
    float pr[4];
    #pragma unroll
    for (int r = 0; r < 4; r++) {
        float v = acc[r] + b2[c];
        v = v >= 0.f ? v : 0.01f * v;
        pr[r] = v * w3;
    }
    #pragma unroll
    for (int r = 0; r < 4; r++)
        for (int o = 32; o; o >>= 1) pr[r] += __shfl_down(pr[r], o);
    int w = tid >> 6;
    if ((tid & 63) == 0) {
        #pragma unroll
        for (int r = 0; r < 4; r++) red[w][r] = pr[r];
    }
    __syncthreads();
    if (tid < 8) {
        int rg2 = tid >> 2, r = tid & 3;
        float s = red[rg2 * 2][r] + red[rg2 * 2 + 1][r] + b3[0];
        score[p0 + rg2 * 4 + r] = s;
    }
}

extern "C" void kernel_launch(void* const* d_in, const int* in_sizes, int n_in,
                              void* d_out, int out_size, void* d_ws, size_t ws_size,
                              hipStream_t stream) {
    const float* x_skill = (const float*)d_in[0];
    const float* x_job   = (const float*)d_in[1];
    const float* x_resume= (const float*)d_in[2];
    const float* W_rel   = (const float*)d_in[3];
    const float* b_rel   = (const float*)d_in[4];
    const float* W_root  = (const float*)d_in[5];
    const float* W_gs    = (const float*)d_in[6];
    const float* W_gd    = (const float*)d_in[7];
    const float* att_s   = (const float*)d_in[8];
    const float* att_d   = (const float*)d_in[9];
    const float* b_gat   = (const float*)d_in[10];
    const float* W1      = (const float*)d_in[11];
    const float* b1      = (const float*)d_in[12];
    const float* W2      = (const float*)d_in[13];
    const float* b2      = (const float*)d_in[14];
    const float* W3      = (const float*)d_in[15];
    const float* b3      = (const float*)d_in[16];
    const int* esj = (const int*)d_in[17];
    const int* edj = (const int*)d_in[18];
    const int* esr = (const int*)d_in[19];
    const int* edr = (const int*)d_in[20];

    const int NS = in_sizes[0] / D_;
    const int NP = in_sizes[1] / D_;
    const int EJ = in_sizes[17];
    const int ER = in_sizes[19];

    float* score = (float*)d_out;
    float* alpha = score + NP;

    char* ws = (char*)d_ws;
    size_t off = 0;
    auto alloc = [&](size_t bytes) -> void* {
        void* p = ws + off;
        off = (off + bytes + 255) & ~(size_t)255;
        return p;
    };

    int* cnt_j  = (int*)alloc((size_t)4 * NP * sizeof(int));
    int* fill_j = cnt_j + NP;
    int* cnt_r  = cnt_j + 2 * NP;
    int* fill_r = cnt_j + 3 * NP;
    int* off_j  = (int*)alloc((size_t)(NP + 1) * sizeof(int));
    int* off_r  = (int*)alloc((size_t)(NP + 1) * sizeof(int));
    int* srcv_j = (int*)alloc((size_t)EJ * sizeof(int));
    int* sid_r  = (int*)alloc((size_t)ER * sizeof(int));
    int* srcv_r = (int*)alloc((size_t)ER * sizeof(int));
    float* Vsrc = (float*)alloc((size_t)D_ * H_ * 4);
    float* Vdst = (float*)alloc((size_t)D_ * H_ * 4);
    float* a_src= (float*)alloc((size_t)NS * H_ * 4);
    float* a_dst= (float*)alloc((size_t)NP * H_ * 4);
    unsigned short* cat_in = (unsigned short*)alloc((size_t)NP * 2 * D_ * 2);
    unsigned short* aggatt = (unsigned short*)alloc((size_t)NP * H_ * D_ * 2);
    unsigned short* BT1    = (unsigned short*)alloc((size_t)D_ * 2 * D_ * 2);
    unsigned short* BTg    = (unsigned short*)alloc((size_t)D_ * H_ * D_ * 2);
    unsigned short* BTw1   = (unsigned short*)alloc((size_t)512 * 2 * D_ * 2);
    unsigned short* hcat   = (unsigned short*)alloc((size_t)NP * 2 * D_ * 2);
    float* Pbuf = (float*)alloc((size_t)5 * NP * D_ * 4);
    unsigned* xsb = (unsigned*)Pbuf;   // alias: xsb dead before first GEMM writes Pbuf

    hipMemsetAsync(cnt_j, 0, (size_t)4 * NP * sizeof(int), stream);
    hipMemsetAsync(Vsrc, 0, (size_t)D_ * H_ * sizeof(float), stream);

    int egrid = (EJ + ER + 255) / 256;
    const int NPREP = D_ + 4608 + 576 + 576 + 384;   // 7680

    // merged: Vdst + all transposes + Vsrc + edge count
    k_prep<<<NPREP + egrid, 256, 0, stream>>>(
        W_gd, att_d, Vdst, W_gs, att_s, Vsrc, BTg, W_rel, W_root, BT1, W1, BTw1,
        edj, EJ, edr, ER, cnt_j, cnt_r);

    // merged: a_src/a_dst/xsb + the two scan blocks
    k_a2<<<NS + NP + 2, 256, 0, stream>>>(x_skill, x_resume, Vsrc, Vdst, a_src, a_dst, xsb,
                                          NS, NP, cnt_j, off_j, cnt_r, off_r);

    k_scatter<<<egrid, 256, 0, stream>>>(edj, esj, EJ, edr, esr, ER,
                                         off_j, fill_j, srcv_j,
                                         off_r, fill_r, sid_r, srcv_r);

    // merged: both aggregates + inlined segment softmax (writes alpha output)
    k_aggs<<<dim3(NP, 6), 256, 0, stream>>>(xsb, srcv_j, cnt_j, off_j,
                                            srcv_r, sid_r, cnt_r, off_r,
                                            a_src, a_dst, x_job,
                                            (unsigned*)cat_in, (unsigned*)aggatt, alpha);

    const int MN_f = NP * D_;
    const int MN_1 = NP * 512;

    // hcat[:, :D] = leaky([agg|x_job] @ [W_rel;W_root] + b_rel)   K=3072 (96 steps), S=5 (480 blk)
    gemm_sk<<<dim3(D_ / 128, NP / 256, 5), 512, 0, stream>>>(
        cat_in, 2 * D_, BT1, 2 * D_, Pbuf, D_, 19, 1);
    k_reduce<1><<<MN_f / 1024, 256, 0, stream>>>(Pbuf, 5, MN_f, D_, hcat, 2 * D_, b_rel, 1.f, 1);

    // hcat[:, D:] = leaky((1/H) * aggatt @ Wstack + b_gat)        K=12288 (384 steps), S=5 (480 blk)
    gemm_sk<<<dim3(D_ / 128, NP / 256, 5), 512, 0, stream>>>(
        aggatt, H_ * D_, BTg, H_ * D_, Pbuf, D_, 76, 4);
    k_reduce<1><<<MN_f / 1024, 256, 0, stream>>>(Pbuf, 5, MN_f, D_, hcat + D_, 2 * D_, b_gat, 1.f / H_, 1);

    // h1 partials (K=3072, 96 steps, S=8, 256 blk) -> fused reduce inside k_mlp2
    gemm_sk<<<dim3(512 / 128, NP / 256, 8), 512, 0, stream>>>(
        hcat, 2 * D_, BTw1, 2 * D_, Pbuf, 512, 12, 0);

    // fused: reduce(8 slabs) + b1 + leaky + MLP2 + score
    k_mlp2<<<NP / 8, 256, 0, stream>>>(Pbuf, MN_1, b1, W2, b2, W3, b3, score);
}

// Round 15
// 379.419 us; speedup vs baseline: 1.0629x; 1.0629x over previous
//
#include <hip/hip_runtime.h>

#define D_ 1536
#define H_ 8

typedef __attribute__((ext_vector_type(8))) short bf16x8;
typedef __attribute__((ext_vector_type(4))) float f32x4;

__device__ __forceinline__ unsigned short f2bf(float f) {
    unsigned u = __builtin_bit_cast(unsigned, f);
    unsigned r = (u + 0x7fffu + ((u >> 16) & 1u)) >> 16;
    return (unsigned short)r;
}

__device__ __forceinline__ unsigned pack2bf(float a, float b) {
    return (unsigned)f2bf(a) | ((unsigned)f2bf(b) << 16);
}

__device__ __forceinline__ float bflo(unsigned u) { return __builtin_bit_cast(float, u << 16); }
__device__ __forceinline__ float bfhi(unsigned u) { return __builtin_bit_cast(float, u & 0xffff0000u); }

__device__ __forceinline__ void gload16(const void* g, void* l) {
    __builtin_amdgcn_global_load_lds((const __attribute__((address_space(1))) void*)g,
                                     (__attribute__((address_space(3))) void*)l, 16, 0, 0);
}

// =================== merged preprocessing: Vdst + transposes + Vsrc + edge COUNT ============
__global__ __launch_bounds__(256) void k_prep(const float* __restrict__ W_gd,
                                              const float* __restrict__ att_d,
                                              float* __restrict__ Vdst,
                                              const float* __restrict__ W_gs,
                                              const float* __restrict__ att_s,
                                              float* __restrict__ Vsrc,
                                              unsigned short* __restrict__ BTg,
                                              const float* __restrict__ W_rel,
                                              const float* __restrict__ W_root,
                                              unsigned short* __restrict__ BT1,
                                              const float* __restrict__ W1,
                                              unsigned short* __restrict__ BTw1,
                                              const int* __restrict__ edj, int EJ,
                                              const int* __restrict__ edr, int ER,
                                              int* cnt_j, int* cnt_r) {
    __shared__ float t[64][65];
    __shared__ float red[4][H_];
    int r = blockIdx.x;

    if (r < D_) {
        int d = r;
        const float4* wr = (const float4*)(W_gd + (size_t)d * (H_ * D_));
        int tid = threadIdx.x;
        float part[H_];
        #pragma unroll
        for (int h = 0; h < H_; h++) {
            const float4* ar = (const float4*)(att_d + h * D_);
            float4 w0 = wr[h * 384 + tid];
            float4 a0 = ar[tid];
            float s = w0.x * a0.x + w0.y * a0.y + w0.z * a0.z + w0.w * a0.w;
            if (tid < 128) {
                float4 w1 = wr[h * 384 + 256 + tid];
                float4 a1 = ar[256 + tid];
                s += w1.x * a1.x + w1.y * a1.y + w1.z * a1.z + w1.w * a1.w;
            }
            part[h] = s;
        }
        int lane = tid & 63, w = tid >> 6;
        #pragma unroll
        for (int h = 0; h < H_; h++) {
            float v = part[h];
            for (int o = 32; o; o >>= 1) v += __shfl_down(v, o);
            if (lane == 0) red[w][h] = v;
        }
        __syncthreads();
        if (tid < H_) Vdst[d * H_ + tid] = red[0][tid] + red[1][tid] + red[2][tid] + red[3][tid];
        return;
    }
    r -= D_;

    if (r >= 6144) {
        int i = (r - 6144) * 256 + threadIdx.x;
        if (i < EJ) atomicAdd(&cnt_j[edj[i]], 1);
        else if (i < EJ + ER) atomicAdd(&cnt_r[edr[i - EJ]], 1);
        return;
    }

    const float* in; int ldin; unsigned short* out; int ldout; int nx; int gatb;
    if (r < 4608)               { in = W_gs;  ldin = 0;   out = BTg;      ldout = H_ * D_; nx = 24; gatb = 1; }
    else if ((r -= 4608) < 576) { in = W_rel; ldin = D_;  out = BT1;      ldout = 2 * D_;  nx = 24; gatb = 0; }
    else if ((r -= 576) < 576)  { in = W_root;ldin = D_;  out = BT1 + D_; ldout = 2 * D_;  nx = 24; gatb = 0; }
    else { r -= 576;              in = W1;    ldin = 512; out = BTw1;     ldout = 2 * D_;  nx = 8;  gatb = 0; }

    int n0 = (r % nx) * 64, k0 = (r / nx) * 64;
    int tx = threadIdx.x & 63, ty = threadIdx.x >> 6;
    #pragma unroll
    for (int i = 0; i < 16; i++) {
        int k = k0 + ty + i * 4;
        const float* rp;
        if (gatb) {
            int d2 = k % D_, h = k / D_;
            rp = in + (size_t)d2 * (H_ * D_) + (size_t)h * D_;
        } else {
            rp = in + (size_t)k * ldin;
        }
        t[ty + i * 4][tx] = rp[n0 + tx];
    }
    __syncthreads();
    int tx2 = threadIdx.x & 31, ty2 = threadIdx.x >> 5;
    #pragma unroll
    for (int i = 0; i < 8; i++) {
        int nl = ty2 + i * 8;
        unsigned v = pack2bf(t[tx2 * 2][nl], t[tx2 * 2 + 1][nl]);
        *(unsigned*)(out + (size_t)(n0 + nl) * ldout + k0 + tx2 * 2) = v;
    }
    if (gatb) {
        int h = k0 / D_, d2b = k0 - h * D_;
        int kl = threadIdx.x >> 2, q = threadIdx.x & 3;
        const float* ar = att_s + (size_t)h * D_ + n0 + q * 16;
        float s = 0.f;
        #pragma unroll
        for (int i = 0; i < 16; i++) s += t[kl][q * 16 + i] * ar[i];
        s += __shfl_xor(s, 1);
        s += __shfl_xor(s, 2);
        if (q == 0) atomicAdd(&Vsrc[(size_t)(d2b + kl) * H_ + h], s);
    }
}

// ---- merged: a_src/a_dst projections (+ xsb) AND the two prefix-sum scan blocks ----
__global__ __launch_bounds__(256) void k_a2(const float* __restrict__ xs,
                                            const float* __restrict__ xr,
                                            const float* __restrict__ Vs,
                                            const float* __restrict__ Vd,
                                            float* __restrict__ a_s,
                                            float* __restrict__ a_d,
                                            unsigned* __restrict__ xb, int NS, int NPn,
                                            const int* __restrict__ cnt_j, int* off_j,
                                            const int* __restrict__ cnt_r, int* off_r) {
    int n = blockIdx.x;
    if (n >= NS + NPn) {
        if (threadIdx.x >= 64) return;
        int which = n - NS - NPn;
        const int* cnt = which ? cnt_r : cnt_j;
        int* off = which ? off_r : off_j;
        int lane = threadIdx.x;
        int chunk = (NPn + 63) / 64;
        int base = lane * chunk;
        int sum = 0;
        for (int i = 0; i < chunk; i++) { int idx = base + i; if (idx < NPn) sum += cnt[idx]; }
        int incl = sum;
        for (int o = 1; o < 64; o <<= 1) { int t = __shfl_up(incl, o); if (lane >= o) incl += t; }
        int run = incl - sum;
        for (int i = 0; i < chunk; i++) { int idx = base + i; if (idx < NPn) { off[idx] = run; run += cnt[idx]; } }
        if (lane == 63) off[NPn] = run;
        return;
    }
    int skill = n < NS;
    int row = skill ? n : n - NS;
    const float2* xrow = (const float2*)(skill ? xs : xr) + (size_t)row * 768;
    const float* V = skill ? Vs : Vd;
    float* out = (skill ? a_s : a_d) + (size_t)row * H_;
    unsigned* ob = xb + (size_t)row * 768;
    float part[H_] = {};
    #pragma unroll
    for (int j = 0; j < 3; j++) {
        int e = threadIdx.x + j * 256;
        float2 v = xrow[e];
        if (skill) ob[e] = pack2bf(v.x, v.y);
        const float* vp = V + (size_t)(2 * e) * H_;
        #pragma unroll
        for (int h = 0; h < H_; h++) part[h] += v.x * vp[h] + v.y * vp[h + H_];
    }
    __shared__ float red[4][H_];
    int lane = threadIdx.x & 63, w = threadIdx.x >> 6;
    #pragma unroll
    for (int h = 0; h < H_; h++) {
        float v = part[h];
        for (int o = 32; o; o >>= 1) v += __shfl_down(v, o);
        if (lane == 0) red[w][h] = v;
    }
    __syncthreads();
    if (threadIdx.x < H_) out[threadIdx.x] =
        red[0][threadIdx.x] + red[1][threadIdx.x] + red[2][threadIdx.x] + red[3][threadIdx.x];
}

// scatter: sorted-order edge ids (resume) + sorted-order SOURCE ids (both)
__global__ void k_scatter(const int* __restrict__ dj, const int* __restrict__ sj, int ej,
                          const int* __restrict__ dr, const int* __restrict__ sr, int er,
                          const int* __restrict__ off_j, int* fill_j, int* srcv_j,
                          const int* __restrict__ off_r, int* fill_r, int* sid_r, int* srcv_r) {
    int i = blockIdx.x * blockDim.x + threadIdx.x;
    if (i < ej) {
        int p = dj[i];
        int slot = atomicAdd(&fill_j[p], 1);
        srcv_j[off_j[p] + slot] = sj[i];
    } else if (i < ej + er) {
        int e = i - ej;
        int p = dr[e];
        int slot = atomicAdd(&fill_r[p], 1);
        int idx = off_r[p] + slot;
        sid_r[idx] = e;
        srcv_r[idx] = sr[e];
    }
}

// ---- GAT segment softmax -> alpha (original order, output) + alpha_s (sorted order) ----
__global__ void k_softmax(const float* __restrict__ a_src, const float* __restrict__ a_dst,
                          const int* __restrict__ srcv, const int* __restrict__ sid,
                          const int* __restrict__ cnt, const int* __restrict__ off,
                          float* __restrict__ alpha_out, float* __restrict__ alpha_s) {
    int p = blockIdx.x;
    int n = cnt[p], o = off[p];
    if (n == 0) return;
    int lane = threadIdx.x;
    float4 ad0 = *(const float4*)(a_dst + (size_t)p * H_);
    float4 ad1 = *(const float4*)(a_dst + (size_t)p * H_ + 4);
    float adv[8] = {ad0.x, ad0.y, ad0.z, ad0.w, ad1.x, ad1.y, ad1.z, ad1.w};
    if (n <= 64) {
        int e = 0;
        float v[8];
        if (lane < n) {
            e = sid[o + lane];
            int s = srcv[o + lane];
            float4 s0 = *(const float4*)(a_src + (size_t)s * H_);
            float4 s1 = *(const float4*)(a_src + (size_t)s * H_ + 4);
            float sv[8] = {s0.x, s0.y, s0.z, s0.w, s1.x, s1.y, s1.z, s1.w};
            #pragma unroll
            for (int h = 0; h < H_; h++) {
                float t = sv[h] + adv[h];
                v[h] = t >= 0.f ? t : 0.2f * t;
            }
        } else {
            #pragma unroll
            for (int h = 0; h < H_; h++) v[h] = -3.4e38f;
        }
        float ex[8];
        #pragma unroll
        for (int h = 0; h < H_; h++) {
            float m = v[h];
            for (int o2 = 32; o2; o2 >>= 1) m = fmaxf(m, __shfl_xor(m, o2));
            float ev = (lane < n) ? expf(v[h] - m) : 0.f;
            float s = ev;
            for (int o2 = 32; o2; o2 >>= 1) s += __shfl_xor(s, o2);
            ex[h] = ev / (s + 1e-16f);
        }
        if (lane < n) {
            *(float4*)(alpha_out + (size_t)e * H_) = make_float4(ex[0], ex[1], ex[2], ex[3]);
            *(float4*)(alpha_out + (size_t)e * H_ + 4) = make_float4(ex[4], ex[5], ex[6], ex[7]);
            *(float4*)(alpha_s + (size_t)(o + lane) * H_) = make_float4(ex[0], ex[1], ex[2], ex[3]);
            *(float4*)(alpha_s + (size_t)(o + lane) * H_ + 4) = make_float4(ex[4], ex[5], ex[6], ex[7]);
        }
    } else {
        #pragma unroll 1
        for (int h = 0; h < H_; h++) {
            float ad = adv[h];
            float m = -3.4e38f;
            for (int i = lane; i < n; i += 64) {
                float v = a_src[(size_t)srcv[o + i] * H_ + h] + ad;
                v = v >= 0.f ? v : 0.2f * v;
                m = fmaxf(m, v);
            }
            for (int o2 = 32; o2; o2 >>= 1) m = fmaxf(m, __shfl_xor(m, o2));
            float s = 0.f;
            for (int i = lane; i < n; i += 64) {
                float v = a_src[(size_t)srcv[o + i] * H_ + h] + ad;
                v = v >= 0.f ? v : 0.2f * v;
                s += expf(v - m);
            }
            for (int o2 = 32; o2; o2 >>= 1) s += __shfl_xor(s, o2);
            float inv = 1.f / (s + 1e-16f);
            for (int i = lane; i < n; i += 64) {
                float v = a_src[(size_t)srcv[o + i] * H_ + h] + ad;
                v = v >= 0.f ? v : 0.2f * v;
                float a = expf(v - m) * inv;
                alpha_out[(size_t)sid[o + i] * H_ + h] = a;
                alpha_s[(size_t)(o + i) * H_ + h] = a;
            }
        }
    }
}

// ---- merged aggregates: grid (NP, 6). y<3: GraphConv cols; y>=3: attention cols ----
__global__ __launch_bounds__(256) void k_aggs(const unsigned* __restrict__ xb,
                                              const int* __restrict__ srcv_j,
                                              const int* __restrict__ cnt_j, const int* __restrict__ off_j,
                                              const int* __restrict__ srcv_r,
                                              const int* __restrict__ cnt_r, const int* __restrict__ off_r,
                                              const float* __restrict__ alpha_s,
                                              const float* __restrict__ x_job,
                                              unsigned* __restrict__ cat_u,
                                              unsigned* __restrict__ aggatt_u) {
    int p = blockIdx.x;
    if (blockIdx.y < 3) {
        int col = blockIdx.y * 256 + threadIdx.x;
        int n = cnt_j[p], o = off_j[p];
        float2 acc = {0.f, 0.f};
        int i = 0;
        for (; i + 2 <= n; i += 2) {
            unsigned v0 = xb[(size_t)srcv_j[o + i] * 768 + col];
            unsigned v1 = xb[(size_t)srcv_j[o + i + 1] * 768 + col];
            acc.x += bflo(v0) + bflo(v1);
            acc.y += bfhi(v0) + bfhi(v1);
        }
        if (i < n) {
            unsigned v = xb[(size_t)srcv_j[o + i] * 768 + col];
            acc.x += bflo(v); acc.y += bfhi(v);
        }
        unsigned* orow = cat_u + (size_t)p * 1536;
        orow[col] = pack2bf(acc.x, acc.y);
        float2 vj = ((const float2*)x_job)[(size_t)p * 768 + col];
        orow[768 + col] = pack2bf(vj.x, vj.y);
    } else {
        int col = (blockIdx.y - 3) * 256 + threadIdx.x;
        int n = cnt_r[p], o = off_r[p];
        const float* as = alpha_s + (size_t)o * H_;
        float2 acc[H_] = {};
        int i = 0;
        for (; i + 2 <= n; i += 2) {
            unsigned v0 = xb[(size_t)srcv_r[o + i] * 768 + col];
            unsigned v1 = xb[(size_t)srcv_r[o + i + 1] * 768 + col];
            float l0 = bflo(v0), h0 = bfhi(v0), l1 = bflo(v1), h1 = bfhi(v1);
            const float* a0 = as + (size_t)i * H_;
            const float* a1 = a0 + H_;
            #pragma unroll
            for (int h = 0; h < H_; h++) {
                float w0 = a0[h], w1 = a1[h];
                acc[h].x += w0 * l0 + w1 * l1;
                acc[h].y += w0 * h0 + w1 * h1;
            }
        }
        if (i < n) {
            unsigned v0 = xb[(size_t)srcv_r[o + i] * 768 + col];
            float l0 = bflo(v0), h0 = bfhi(v0);
            const float* a0 = as + (size_t)i * H_;
            #pragma unroll
            for (int h = 0; h < H_; h++) { acc[h].x += a0[h] * l0; acc[h].y += a0[h] * h0; }
        }
        unsigned* orow = aggatt_u + (size_t)p * (H_ * 768);
        #pragma unroll
        for (int h = 0; h < H_; h++)
            orow[h * 768 + col] = pack2bf(acc[h].x, acc[h].y);
    }
}

// ---------------- bf16 MFMA GEMM (R11-exact): BM=256 BN=128, 8 waves, split-K, 3-buf 2-deep --
__global__ __launch_bounds__(512, 4) void gemm_sk(const unsigned short* __restrict__ A, int lda,
                                                  const unsigned short* __restrict__ BT, int ldb,
                                                  float* __restrict__ P, int N, int bs, int extra) {
    __shared__ unsigned short As[3][256 * 32];
    __shared__ unsigned short Bs[3][128 * 32];
    int tid = threadIdx.x;
    int lane = tid & 63, wid = tid >> 6;

    int nwg = gridDim.x * gridDim.y;
    int bidh = blockIdx.y * gridDim.x + blockIdx.x;
    int swz = (bidh & 7) * (nwg >> 3) + (bidh >> 3);
    int bn = (swz % gridDim.x) * 128;
    int bm = (swz / gridDim.x) * 256;

    int z = blockIdx.z;
    int nt = bs + (z < extra);
    int kb = z * bs + min(z, extra);
    int kbase = kb * 32;

    int wr = wid >> 1, wc = wid & 1;            // 4 x 2 wave grid, wave tile 64x64
    int fr = lane & 15, g = lane >> 4;

    int ra0 = tid >> 2, sa0 = tid & 3;
    int ra1 = (tid + 512) >> 2;
    int sg_a0 = sa0 ^ ((ra0 >> 1) & 3);
    int sg_a1 = sa0 ^ ((ra1 >> 1) & 3);
    int sg_b = sg_a0;

    f32x4 acc[4][4] = {};

    auto stage = [&](int buf, int k0) {
        gload16(A + (size_t)(bm + ra0) * lda + k0 + sg_a0 * 8, &As[buf][tid * 8]);
        gload16(A + (size_t)(bm + ra1) * lda + k0 + sg_a1 * 8, &As[buf][(tid + 512) * 8]);
        gload16(BT + (size_t)(bn + ra0) * ldb + k0 + sg_b * 8, &Bs[buf][tid * 8]);
    };

    stage(0, kbase);
    if (nt > 1) stage(1, kbase + 32);
    for (int t = 0; t < nt; t++) {
        if (t + 2 < nt) {
            stage((t + 2) % 3, kbase + (t + 2) * 32);
            asm volatile("s_waitcnt vmcnt(6)" ::: "memory");   // oldest stage (t) landed
        } else if (t + 1 < nt) {
            asm volatile("s_waitcnt vmcnt(3)" ::: "memory");
        } else {
            asm volatile("s_waitcnt vmcnt(0)" ::: "memory");
        }
        __builtin_amdgcn_s_barrier();
        __builtin_amdgcn_sched_barrier(0);
        int cur = t % 3;
        bf16x8 a[4], b[4];
        #pragma unroll
        for (int mi = 0; mi < 4; mi++) {
            int row = wr * 64 + mi * 16 + fr;
            a[mi] = *(const bf16x8*)(&As[cur][row * 32 + ((g ^ ((row >> 1) & 3)) * 8)]);
        }
        #pragma unroll
        for (int ni = 0; ni < 4; ni++) {
            int row = wc * 64 + ni * 16 + fr;
            b[ni] = *(const bf16x8*)(&Bs[cur][row * 32 + ((g ^ ((row >> 1) & 3)) * 8)]);
        }
        __builtin_amdgcn_s_setprio(1);
        #pragma unroll
        for (int mi = 0; mi < 4; mi++)
            #pragma unroll
            for (int ni = 0; ni < 4; ni++)
                acc[mi][ni] = __builtin_amdgcn_mfma_f32_16x16x32_bf16(a[mi], b[ni], acc[mi][ni], 0, 0, 0);
        __builtin_amdgcn_s_setprio(0);
        __builtin_amdgcn_s_barrier();
        __builtin_amdgcn_sched_barrier(0);
    }

    size_t MN = (size_t)N * (size_t)(gridDim.y * 256);
    float* Pz = P + (size_t)z * MN;
    #pragma unroll
    for (int mi = 0; mi < 4; mi++) {
        int r0 = bm + wr * 64 + mi * 16 + (lane >> 4) * 4;
        #pragma unroll
        for (int ni = 0; ni < 4; ni++) {
            int c = bn + wc * 64 + ni * 16 + (lane & 15);
            #pragma unroll
            for (int j = 0; j < 4; j++)
                Pz[(size_t)(r0 + j) * N + c] = acc[mi][ni][j];
        }
    }
}

// ---------------- split-K reduce + epilogue (big GEMMs) ----------------
template <int OUT_BF16>
__global__ __launch_bounds__(256) void k_reduce(const float* __restrict__ P, int S, int MN, int N,
                                                void* __restrict__ Cout, int ldc,
                                                const float* __restrict__ bias, float scale,
                                                int useLeaky) {
    int idx = (blockIdx.x * 256 + threadIdx.x) * 4;
    if (idx >= MN) return;
    float4 v = *(const float4*)(P + idx);
    for (int s = 1; s < S; s++) {
        float4 t = *(const float4*)(P + (size_t)s * MN + idx);
        v.x += t.x; v.y += t.y; v.z += t.z; v.w += t.w;
    }
    int m = idx / N, n = idx - m * N;
    float vv[4] = {v.x, v.y, v.z, v.w};
    #pragma unroll
    for (int j = 0; j < 4; j++) {
        float x = vv[j] * scale + bias[n + j];
        if (useLeaky) x = x >= 0.f ? x : 0.01f * x;
        if (OUT_BF16) ((unsigned short*)Cout)[(size_t)m * ldc + n + j] = f2bf(x);
        else ((float*)Cout)[(size_t)m * ldc + n + j] = x;
    }
}

// ---- fused: h1 split-K reduce (8 slabs) + b1 + leaky + MLP2 + score ----
__global__ __launch_bounds__(256) void k_mlp2(const float* __restrict__ P, int MN1,
                                              const float* __restrict__ b1,
                                              const float* __restrict__ W2,
                                              const float* __restrict__ b2,
                                              const float* __restrict__ W3,
                                              const float* __restrict__ b3,
                                              float* __restrict__ score) {
    __shared__ unsigned h1s[8][256];
    __shared__ float red[4][4];
    int p0 = blockIdx.x * 8;
    int tid = threadIdx.x;
    #pragma unroll
    for (int i = 0; i < 8; i++) {
        int idx = tid + i * 256;
        int row = idx >> 8, c2 = idx & 255;
        size_t base = (size_t)(p0 + row) * 512 + 2 * c2;
        float2 v = {0.f, 0.f};
        #pragma unroll
        for (int s = 0; s < 8; s++) {
            float2 t = *(const float2*)(P + (size_t)s * MN1 + base);
            v.x += t.x; v.y += t.y;
        }
        float2 bb = *(const float2*)(b1 + 2 * c2);
        v.x += bb.x; v.y += bb.y;
        v.x = v.x >= 0.f ? v.x : 0.01f * v.x;
        v.y = v.y >= 0.f ? v.y : 0.01f * v.y;
        h1s[row][c2] = pack2bf(v.x, v.y);
    }
    __syncthreads();
    int c = tid & 127, rg = tid >> 7;
    float acc[4] = {};
    for (int k = 0; k < 512; k += 2) {
        float w0 = W2[(size_t)k * 128 + c];
        float w1 = W2[(size_t)(k + 1) * 128 + c];
        #pragma unroll
        for (int r = 0; r < 4; r++) {
            unsigned hv = h1s[rg * 4 + r][k >> 1];
            acc[r] += bflo(hv) * w0 + bfhi(hv) * w1;
        }
    }
    float w3 = W3[c];
    float pr[4];
    #pragma unroll
    for (int r = 0; r < 4; r++) {
        float v = acc[r] + b2[c];
        v = v >= 0.f ? v : 0.01f * v;
        pr[r] = v * w3;
    }
    #pragma unroll
    for (int r = 0; r < 4; r++)
        for (int o = 32; o; o >>= 1) pr[r] += __shfl_down(pr[r], o);
    int w = tid >> 6;
    if ((tid & 63) == 0) {
        #pragma unroll
        for (int r = 0; r < 4; r++) red[w][r] = pr[r];
    }
    __syncthreads();
    if (tid < 8) {
        int rg2 = tid >> 2, r = tid & 3;
        float s = red[rg2 * 2][r] + red[rg2 * 2 + 1][r] + b3[0];
        score[p0 + rg2 * 4 + r] = s;
    }
}

extern "C" void kernel_launch(void* const* d_in, const int* in_sizes, int n_in,
                              void* d_out, int out_size, void* d_ws, size_t ws_size,
                              hipStream_t stream) {
    const float* x_skill = (const float*)d_in[0];
    const float* x_job   = (const float*)d_in[1];
    const float* x_resume= (const float*)d_in[2];
    const float* W_rel   = (const float*)d_in[3];
    const float* b_rel   = (const float*)d_in[4];
    const float* W_root  = (const float*)d_in[5];
    const float* W_gs    = (const float*)d_in[6];
    const float* W_gd    = (const float*)d_in[7];
    const float* att_s   = (const float*)d_in[8];
    const float* att_d   = (const float*)d_in[9];
    const float* b_gat   = (const float*)d_in[10];
    const float* W1      = (const float*)d_in[11];
    const float* b1      = (const float*)d_in[12];
    const float* W2      = (const float*)d_in[13];
    const float* b2      = (const float*)d_in[14];
    const float* W3      = (const float*)d_in[15];
    const float* b3      = (const float*)d_in[16];
    const int* esj = (const int*)d_in[17];
    const int* edj = (const int*)d_in[18];
    const int* esr = (const int*)d_in[19];
    const int* edr = (const int*)d_in[20];

    const int NS = in_sizes[0] / D_;
    const int NP = in_sizes[1] / D_;
    const int EJ = in_sizes[17];
    const int ER = in_sizes[19];

    float* score = (float*)d_out;
    float* alpha = score + NP;

    char* ws = (char*)d_ws;
    size_t off = 0;
    auto alloc = [&](size_t bytes) -> void* {
        void* p = ws + off;
        off = (off + bytes + 255) & ~(size_t)255;
        return p;
    };

    int* cnt_j  = (int*)alloc((size_t)4 * NP * sizeof(int));
    int* fill_j = cnt_j + NP;
    int* cnt_r  = cnt_j + 2 * NP;
    int* fill_r = cnt_j + 3 * NP;
    int* off_j  = (int*)alloc((size_t)(NP + 1) * sizeof(int));
    int* off_r  = (int*)alloc((size_t)(NP + 1) * sizeof(int));
    int* srcv_j = (int*)alloc((size_t)EJ * sizeof(int));
    int* sid_r  = (int*)alloc((size_t)ER * sizeof(int));
    int* srcv_r = (int*)alloc((size_t)ER * sizeof(int));
    float* alpha_s = (float*)alloc((size_t)ER * H_ * sizeof(float));
    float* Vsrc = (float*)alloc((size_t)D_ * H_ * 4);
    float* Vdst = (float*)alloc((size_t)D_ * H_ * 4);
    float* a_src= (float*)alloc((size_t)NS * H_ * 4);
    float* a_dst= (float*)alloc((size_t)NP * H_ * 4);
    unsigned short* cat_in = (unsigned short*)alloc((size_t)NP * 2 * D_ * 2);
    unsigned short* aggatt = (unsigned short*)alloc((size_t)NP * H_ * D_ * 2);
    unsigned short* BT1    = (unsigned short*)alloc((size_t)D_ * 2 * D_ * 2);
    unsigned short* BTg    = (unsigned short*)alloc((size_t)D_ * H_ * D_ * 2);
    unsigned short* BTw1   = (unsigned short*)alloc((size_t)512 * 2 * D_ * 2);
    unsigned short* hcat   = (unsigned short*)alloc((size_t)NP * 2 * D_ * 2);
    float* Pbuf = (float*)alloc((size_t)5 * NP * D_ * 4);
    unsigned* xsb = (unsigned*)Pbuf;   // alias: xsb dead before first GEMM writes Pbuf

    hipMemsetAsync(cnt_j, 0, (size_t)4 * NP * sizeof(int), stream);
    hipMemsetAsync(Vsrc, 0, (size_t)D_ * H_ * sizeof(float), stream);

    int egrid = (EJ + ER + 255) / 256;
    const int NPREP = D_ + 4608 + 576 + 576 + 384;   // 7680

    // merged: Vdst + all transposes + Vsrc + edge count
    k_prep<<<NPREP + egrid, 256, 0, stream>>>(
        W_gd, att_d, Vdst, W_gs, att_s, Vsrc, BTg, W_rel, W_root, BT1, W1, BTw1,
        edj, EJ, edr, ER, cnt_j, cnt_r);

    // merged: a_src/a_dst/xsb + the two scan blocks
    k_a2<<<NS + NP + 2, 256, 0, stream>>>(x_skill, x_resume, Vsrc, Vdst, a_src, a_dst, xsb,
                                          NS, NP, cnt_j, off_j, cnt_r, off_r);

    k_scatter<<<egrid, 256, 0, stream>>>(edj, esj, EJ, edr, esr, ER,
                                         off_j, fill_j, srcv_j,
                                         off_r, fill_r, sid_r, srcv_r);

    k_softmax<<<NP, 64, 0, stream>>>(a_src, a_dst, srcv_r, sid_r, cnt_r, off_r, alpha, alpha_s);
    k_aggs<<<dim3(NP, 6), 256, 0, stream>>>(xsb, srcv_j, cnt_j, off_j,
                                            srcv_r, cnt_r, off_r, alpha_s, x_job,
                                            (unsigned*)cat_in, (unsigned*)aggatt);

    const int MN_f = NP * D_;
    const int MN_1 = NP * 512;

    // hcat[:, :D] = leaky([agg|x_job] @ [W_rel;W_root] + b_rel)   K=3072 (96 steps), S=5 (480 blk)
    gemm_sk<<<dim3(D_ / 128, NP / 256, 5), 512, 0, stream>>>(
        cat_in, 2 * D_, BT1, 2 * D_, Pbuf, D_, 19, 1);
    k_reduce<1><<<MN_f / 1024, 256, 0, stream>>>(Pbuf, 5, MN_f, D_, hcat, 2 * D_, b_rel, 1.f, 1);

    // hcat[:, D:] = leaky((1/H) * aggatt @ Wstack + b_gat)        K=12288 (384 steps), S=5 (480 blk)
    gemm_sk<<<dim3(D_ / 128, NP / 256, 5), 512, 0, stream>>>(
        aggatt, H_ * D_, BTg, H_ * D_, Pbuf, D_, 76, 4);
    k_reduce<1><<<MN_f / 1024, 256, 0, stream>>>(Pbuf, 5, MN_f, D_, hcat + D_, 2 * D_, b_gat, 1.f / H_, 1);

    // h1 partials (K=3072, 96 steps, S=8, 256 blk) -> fused reduce inside k_mlp2
    gemm_sk<<<dim3(512 / 128, NP / 256, 8), 512, 0, stream>>>(
        hcat, 2 * D_, BTw1, 2 * D_, Pbuf, 512, 12, 0);

    // fused: reduce(8 slabs) + b1 + leaky + MLP2 + score
    k_mlp2<<<NP / 8, 256, 0, stream>>>(Pbuf, MN_1, b1, W2, b2, W3, b3, score);
}